// Round 4
// baseline (1417.683 us; speedup 1.0000x reference)
//
#include <hip/hip_runtime.h>
#include <hip/hip_bf16.h>

// ---------------------------------------------------------------------------
// EdgeClassifierGNN: 2x SAGEConv(mean)+BN+ReLU, then 3-layer edge MLP.
// Trick 1: lin_l before mean-aggregation (64-wide gather).
// Trick 2: edge-MLP layer 1 split: z1 = relu(u[src] + v[dst] + B1*attr).
// Trick 3: CSR by dst (atomic-free aggregation) + dst-ORDERED edge MLP so
//          v[dst] gathers are cache-hot (only u[src] stays random).
// Trick 4: dual-output node GEMMs + BN folded into consumers (scale/shift).
// ---------------------------------------------------------------------------

#define EPS 1e-5f

// ---------------- CSR build ----------------
__global__ __launch_bounds__(256) void k_hist(
    const int* __restrict__ dst, int* __restrict__ deg, int E) {
  int e = blockIdx.x * 256 + threadIdx.x;
  if (e < E) atomicAdd(&deg[dst[e]], 1);
}

// single-block exclusive scan, wave-shfl based (4 barriers per 1024 chunk)
__global__ __launch_bounds__(1024) void k_scan(
    const int* __restrict__ deg, int* __restrict__ rowptr,
    int* __restrict__ cursor, int N) {
  __shared__ int wsum[16];
  __shared__ int carry;
  const int lane = threadIdx.x & 63;
  const int w    = threadIdx.x >> 6;
  if (threadIdx.x == 0) carry = 0;
  __syncthreads();
  for (int base = 0; base < N; base += 1024) {
    int i = base + threadIdx.x;
    int v = (i < N) ? deg[i] : 0;
    int incl = v;
#pragma unroll
    for (int off = 1; off < 64; off <<= 1) {
      int t = __shfl_up(incl, off);
      if (lane >= off) incl += t;
    }
    if (lane == 63) wsum[w] = incl;
    __syncthreads();
    if (w == 0) {
      int ws_ = (lane < 16) ? wsum[lane] : 0;
      int wincl = ws_;
#pragma unroll
      for (int off = 1; off < 16; off <<= 1) {
        int t = __shfl_up(wincl, off);
        if (lane >= off) wincl += t;
      }
      if (lane < 16) wsum[lane] = wincl;
    }
    __syncthreads();
    int woff = carry + (w > 0 ? wsum[w - 1] : 0);
    int excl = woff + incl - v;
    if (i < N) { rowptr[i] = excl; cursor[i] = excl; }
    int tot = wsum[15];
    __syncthreads();
    if (threadIdx.x == 0) carry += tot;
    __syncthreads();
  }
  if (threadIdx.x == 0) rowptr[N] = carry;
}

__global__ __launch_bounds__(256) void k_fill(
    const int* __restrict__ src, const int* __restrict__ dst,
    int* __restrict__ cursor, int* __restrict__ csr_src,
    int* __restrict__ csr_dst, int* __restrict__ csr_eid, int E) {
  int e = blockIdx.x * 256 + threadIdx.x;
  if (e < E) {
    int d = dst[e];
    int pos = atomicAdd(&cursor[d], 1);
    csr_src[pos] = src[e];
    csr_dst[pos] = d;
    csr_eid[pos] = e;
  }
}

// ---------------- dual node GEMMs ----------------
// q[n][f] = dot(x[n][:128], Wl[f]);  p[n][f] = dot(x[n][:128], Wr[f]) + br[f]
__global__ __launch_bounds__(256) void k_lin_dual128(
    const float* __restrict__ x, const float* __restrict__ Wl,
    const float* __restrict__ Wr, const float* __restrict__ br,
    float* __restrict__ q, float* __restrict__ p, int N) {
  __shared__ float w[2][64 * 129];
  for (int idx = threadIdx.x; idx < 64 * 128; idx += 256) {
    int f = idx >> 7, k = idx & 127;
    w[0][f * 129 + k] = Wl[idx];
    w[1][f * 129 + k] = Wr[idx];
  }
  __syncthreads();
  const int f    = threadIdx.x & 63;
  const int half = (threadIdx.x >> 6) & 1;
  const int ns   = threadIdx.x >> 7;
  const float bv = half ? br[f] : 0.f;
  float* o = half ? p : q;
  const float* wp = &w[half][f * 129];
  for (int n = blockIdx.x * 2 + ns; n < N; n += gridDim.x * 2) {
    const float* xr = x + (size_t)n * 128;
    float acc = bv;
#pragma unroll 8
    for (int k = 0; k < 128; ++k) acc += xr[k] * wp[k];
    o[(size_t)n * 64 + f] = acc;
  }
}

// h[k] = relu(hpre[n][k]*scale[k]+shift[k]) applied on the fly (BN fused):
// q[n][f] = dot(h, Wl[f]);  p[n][f] = dot(h, Wr[f]) + br[f]
__global__ __launch_bounds__(256) void k_lin_dual64(
    const float* __restrict__ hpre, const float* __restrict__ stats,
    const float* __restrict__ Wl, const float* __restrict__ Wr,
    const float* __restrict__ br, float* __restrict__ q,
    float* __restrict__ p, int N) {
  __shared__ float w[2][64 * 65];
  __shared__ float sc[64], sh[64];
  for (int idx = threadIdx.x; idx < 64 * 64; idx += 256) {
    int f = idx >> 6, k = idx & 63;
    w[0][f * 65 + k] = Wl[idx];
    w[1][f * 65 + k] = Wr[idx];
  }
  if (threadIdx.x < 64) {
    sc[threadIdx.x] = stats[128 + threadIdx.x];
    sh[threadIdx.x] = stats[192 + threadIdx.x];
  }
  __syncthreads();
  const int f    = threadIdx.x & 63;
  const int half = (threadIdx.x >> 6) & 1;
  const int ns   = threadIdx.x >> 7;
  const float bv = half ? br[f] : 0.f;
  float* o = half ? p : q;
  const float* wp = &w[half][f * 65];
  for (int n = blockIdx.x * 2 + ns; n < N; n += gridDim.x * 2) {
    const float* hr = hpre + (size_t)n * 64;
    float acc = bv;
#pragma unroll 8
    for (int k = 0; k < 64; ++k) {
      float hv = fmaxf(hr[k] * sc[k] + sh[k], 0.f);
      acc += hv * wp[k];
    }
    o[(size_t)n * 64 + f] = acc;
  }
}

// u[n][c] = dot(h, A1[c]) + bm1[c] ; v[n][c] = dot(h, C1[c]); BN fused on h
__global__ __launch_bounds__(256) void k_lin2_dual(
    const float* __restrict__ hpre, const float* __restrict__ stats,
    const float* __restrict__ Wm1, const float* __restrict__ bm1,
    float* __restrict__ u, float* __restrict__ v, int N) {
  __shared__ float wa[128 * 65];
  __shared__ float wc[128 * 65];
  __shared__ float sc[64], sh[64];
  for (int idx = threadIdx.x; idx < 128 * 64; idx += 256) {
    int c = idx >> 6, k = idx & 63;
    wa[c * 65 + k] = Wm1[c * 144 + k];
    wc[c * 65 + k] = Wm1[c * 144 + 80 + k];
  }
  if (threadIdx.x < 64) {
    sc[threadIdx.x] = stats[128 + threadIdx.x];
    sh[threadIdx.x] = stats[192 + threadIdx.x];
  }
  __syncthreads();
  const int c     = threadIdx.x & 127;
  const int which = threadIdx.x >> 7;
  const float bv = which ? 0.f : bm1[c];
  const float* wp = (which ? wc : wa) + c * 65;
  float* o = which ? v : u;
  for (int n = blockIdx.x; n < N; n += gridDim.x) {
    const float* hr = hpre + (size_t)n * 64;
    float acc = bv;
#pragma unroll 8
    for (int k = 0; k < 64; ++k) {
      float hv = fmaxf(hr[k] * sc[k] + sh[k], 0.f);
      acc += hv * wp[k];
    }
    o[(size_t)n * 128 + c] = acc;
  }
}

// ---------------- fused aggregate + mean + residual + BN stats ----------------
__global__ __launch_bounds__(256) void k_agg(
    const float* __restrict__ q, const float* __restrict__ p,
    const int* __restrict__ rowptr, const int* __restrict__ csr_src,
    float* __restrict__ hpre, float* __restrict__ stats, int N) {
  __shared__ float red[512];
  const int f  = threadIdx.x & 63;
  const int ns = threadIdx.x >> 6;
  float lsum = 0.f, lsq = 0.f;
  for (int n = blockIdx.x * 4 + ns; n < N; n += gridDim.x * 4) {
    const int r0 = rowptr[n], r1 = rowptr[n + 1];
    float s0 = 0.f, s1 = 0.f;
    int j = r0;
    for (; j + 1 < r1; j += 2) {
      int a = csr_src[j], b = csr_src[j + 1];
      s0 += q[(size_t)a * 64 + f];
      s1 += q[(size_t)b * 64 + f];
    }
    if (j < r1) s0 += q[(size_t)csr_src[j] * 64 + f];
    float c = (float)(r1 - r0);
    c = c > 1.f ? c : 1.f;
    float v = (s0 + s1) / c + p[(size_t)n * 64 + f];
    hpre[(size_t)n * 64 + f] = v;
    lsum += v;
    lsq  += v * v;
  }
  red[threadIdx.x]       = lsum;
  red[256 + threadIdx.x] = lsq;
  __syncthreads();
  if (threadIdx.x < 64) {
    float ts = red[f] + red[f + 64] + red[f + 128] + red[f + 192];
    float tq = red[256 + f] + red[256 + f + 64] + red[256 + f + 128] + red[256 + f + 192];
    atomicAdd(&stats[f], ts);
    atomicAdd(&stats[64 + f], tq);
  }
}

// stats -> BN scale/shift: scale=g*invstd, shift=be-mean*scale
__global__ void k_finalize(float* stats, const float* __restrict__ g,
                           const float* __restrict__ be, int N) {
  int f = threadIdx.x;  // 64 threads
  float inv_n = 1.0f / (float)N;
  float mean = stats[f] * inv_n;
  float var  = stats[64 + f] * inv_n - mean * mean;
  float s = g[f] * rsqrtf(var + EPS);
  stats[128 + f] = s;
  stats[192 + f] = be[f] - mean * s;
}

// WT[c*R+r] = W[r*C+c]
__global__ void k_transpose(const float* __restrict__ W, float* __restrict__ WT,
                            int R, int C) {
  int idx = blockIdx.x * 256 + threadIdx.x;
  if (idx < R * C) {
    int r = idx / C, c = idx - r * C;
    WT[c * R + r] = W[r * C + c];
  }
}

// BT[k*128+c] = Wm1[c*144 + 64 + k], k<16, c<128
__global__ void k_tbt(const float* __restrict__ Wm1, float* __restrict__ BT) {
  int idx = blockIdx.x * 256 + threadIdx.x;
  if (idx < 16 * 128) {
    int k = idx >> 7, c = idx & 127;
    BT[idx] = Wm1[c * 144 + 64 + k];
  }
}

// ---------------------------------------------------------------------------
// Fused edge MLP over the dst-ORDERED edge list (csr_*). Per 64-edge tile:
//   z1[e][c] = relu(u[csrc[e]][c] + v[cdst[e]][c] + sum_k attr[ceid[e]][k]*BT[k][c])
//   z2 = relu(z1 @ W2T + bm2) ; out[ceid[e]] = z2 @ Wm3.T + bm3
// cdst repeats within a tile -> v gathers hit L1/L2; only u stays random.
// ---------------------------------------------------------------------------
__global__ __launch_bounds__(256, 2) void k_edge(
    const float* __restrict__ u, const float* __restrict__ v,
    const float* __restrict__ attr,
    const int* __restrict__ csrc, const int* __restrict__ cdst,
    const int* __restrict__ ceid,
    const float* __restrict__ W2Tws, const float* __restrict__ BTws,
    const float* __restrict__ bm2, const float* __restrict__ Wm3,
    const float* __restrict__ bm3, float* __restrict__ out, int E) {
  __shared__ __align__(16) float W2Tl[128 * 64];   // [k][j]
  __shared__ __align__(16) float Z1[64 * 132];     // [e][c], pad 128->132
  __shared__ __align__(16) float attrL[64 * 16];   // [e][k]
  __shared__ int   idxL[128];                      // src[0:64], dst[64:128]
  __shared__ int   eidL[64];
  __shared__ float outT[128];                      // [e][o]

  const int tid = threadIdx.x;
  const int c4  = tid & 31;
  const int tx  = tid & 15;
  const int ty  = tid >> 4;

  for (int i = tid; i < 2048; i += 256)
    ((float4*)W2Tl)[i] = ((const float4*)W2Tws)[i];

  const float4* u4  = (const float4*)u;
  const float4* v4  = (const float4*)v;
  const float4* at4 = (const float4*)attr;
  const float4* bt4 = (const float4*)BTws;

  const int nt = (E + 63) >> 6;
  for (int t = blockIdx.x; t < nt; t += gridDim.x) {
    const int e0 = t << 6;
    __syncthreads();   // LDS reuse vs previous iteration / W2T staging

    if (tid < 64) {
      int j = e0 + tid;
      idxL[tid]      = (j < E) ? csrc[j] : 0;
      idxL[64 + tid] = (j < E) ? cdst[j] : 0;
      eidL[tid]      = (j < E) ? ceid[j] : -1;
    }
    if (tid < 128) outT[tid] = bm3[tid & 1];
    float4 breg[16];
#pragma unroll
    for (int k = 0; k < 16; ++k) breg[k] = bt4[k * 32 + c4];
    __syncthreads();

    {  // attr gather by original edge id
      int e = tid >> 2, k4 = tid & 3;
      int eid = eidL[e];
      float4 av = make_float4(0.f, 0.f, 0.f, 0.f);
      if (eid >= 0) av = at4[(size_t)eid * 4 + k4];
      ((float4*)attrL)[tid] = av;
    }
    __syncthreads();

    // ---- layer 1 assembly: 64 edges x 32 float4-chunks ----
#pragma unroll
    for (int it = 0; it < 8; ++it) {
      const int e = it * 8 + (tid >> 5);
      const int col = c4 * 4;
      float4 a = u4[(size_t)idxL[e] * 32 + c4];
      float4 b = v4[(size_t)idxL[64 + e] * 32 + c4];
      float sx = a.x + b.x, sy = a.y + b.y, sz = a.z + b.z, sw = a.w + b.w;
#pragma unroll
      for (int k = 0; k < 16; ++k) {
        float av = attrL[e * 16 + k];
        sx += av * breg[k].x; sy += av * breg[k].y;
        sz += av * breg[k].z; sw += av * breg[k].w;
      }
      float4 r;
      r.x = fmaxf(sx, 0.f); r.y = fmaxf(sy, 0.f);
      r.z = fmaxf(sz, 0.f); r.w = fmaxf(sw, 0.f);
      *(float4*)&Z1[e * 132 + col] = r;
    }
    __syncthreads();

    // ---- layer 2: [64 edges x 64 cols], K=128, 4x4 per thread ----
    float acc[4][4];
#pragma unroll
    for (int c = 0; c < 4; ++c) {
      float bv = bm2[4 * tx + c];
#pragma unroll
      for (int i = 0; i < 4; ++i) acc[i][c] = bv;
    }
    for (int kk = 0; kk < 128; kk += 4) {
      float4 a[4], b[4];
#pragma unroll
      for (int i = 0; i < 4; ++i) a[i] = *(const float4*)&Z1[(4 * ty + i) * 132 + kk];
#pragma unroll
      for (int q = 0; q < 4; ++q) b[q] = *(const float4*)&W2Tl[(kk + q) * 64 + 4 * tx];
#pragma unroll
      for (int i = 0; i < 4; ++i) {
#pragma unroll
        for (int q = 0; q < 4; ++q) {
          float av = (q == 0) ? a[i].x : (q == 1) ? a[i].y : (q == 2) ? a[i].z : a[i].w;
          acc[i][0] += av * b[q].x;
          acc[i][1] += av * b[q].y;
          acc[i][2] += av * b[q].z;
          acc[i][3] += av * b[q].w;
        }
      }
    }

    // ---- fused layer 3: relu(z2) -> partial dot with Wm3, LDS atomics ----
    float w30[4], w31[4];
#pragma unroll
    for (int c = 0; c < 4; ++c) {
      w30[c] = Wm3[4 * tx + c];
      w31[c] = Wm3[64 + 4 * tx + c];
    }
#pragma unroll
    for (int i = 0; i < 4; ++i) {
      float p0 = 0.f, p1 = 0.f;
#pragma unroll
      for (int c = 0; c < 4; ++c) {
        float z = fmaxf(acc[i][c], 0.f);
        p0 += z * w30[c];
        p1 += z * w31[c];
      }
      atomicAdd(&outT[(4 * ty + i) * 2 + 0], p0);
      atomicAdd(&outT[(4 * ty + i) * 2 + 1], p1);
    }
    __syncthreads();

    if (tid < 128) {
      int e = tid >> 1;
      int eid = eidL[e];
      if (eid >= 0) out[(size_t)eid * 2 + (tid & 1)] = outT[tid];
    }
  }
}

extern "C" void kernel_launch(void* const* d_in, const int* in_sizes, int n_in,
                              void* d_out, int out_size, void* d_ws, size_t ws_size,
                              hipStream_t stream) {
  const float* x    = (const float*)d_in[0];
  const int*   ei   = (const int*)d_in[1];
  const float* attr = (const float*)d_in[2];
  const float* W1l  = (const float*)d_in[3];
  const float* b1l  = (const float*)d_in[4];
  const float* W1r  = (const float*)d_in[5];
  const float* g1   = (const float*)d_in[6];
  const float* be1  = (const float*)d_in[7];
  const float* W2l  = (const float*)d_in[8];
  const float* b2l  = (const float*)d_in[9];
  const float* W2r  = (const float*)d_in[10];
  const float* g2   = (const float*)d_in[11];
  const float* be2  = (const float*)d_in[12];
  const float* Wm1  = (const float*)d_in[13];
  const float* bm1  = (const float*)d_in[14];
  const float* Wm2  = (const float*)d_in[15];
  const float* bm2  = (const float*)d_in[16];
  const float* Wm3  = (const float*)d_in[17];
  const float* bm3  = (const float*)d_in[18];
  float* out = (float*)d_out;

  const int N = in_sizes[0] / 128;
  const int E = in_sizes[1] / 2;
  const int* srcI = ei;
  const int* dstI = ei + E;

  float* ws = (float*)d_ws;
  const size_t NF = (size_t)N * 64;
  // five NF-sized float regions (overlaid across phases)
  float* R0 = ws;
  float* R1 = ws + NF;
  float* R2 = ws + 2 * NF;
  float* R3 = ws + 3 * NF;       // R3,R4 = second pair (V)
  float* stats1 = ws + 5 * NF;   // 256
  float* stats2 = stats1 + 256;  // 256
  float* W2Tws  = stats2 + 256;  // 128*64
  float* BTws   = W2Tws + 8192;  // 16*128
  int*   rowptr = (int*)(BTws + 2048);  // N+1
  int*   cursor = rowptr + (N + 1);     // N
  int*   deg    = cursor + N;           // N
  int*   csrsrc = deg + N;              // E
  int*   csrdst = csrsrc + E;           // E
  int*   csreid = csrdst + E;           // E
  float* U = R0;                 // 2*NF (R0+R1)
  float* V = R3;                 // 2*NF (R3+R4)

  hipMemsetAsync(deg, 0, (size_t)N * sizeof(int), stream);
  hipMemsetAsync(stats1, 0, 512 * sizeof(float), stream);  // stats1+stats2

  // ---- CSR build ----
  const int eBlocks = (E + 255) / 256;
  k_hist<<<eBlocks, 256, 0, stream>>>(dstI, deg, E);
  k_scan<<<1, 1024, 0, stream>>>(deg, rowptr, cursor, N);
  k_fill<<<eBlocks, 256, 0, stream>>>(srcI, dstI, cursor, csrsrc, csrdst, csreid, E);

  k_transpose<<<(64 * 128 + 255) / 256, 256, 0, stream>>>(Wm2, W2Tws, 64, 128);
  k_tbt<<<(16 * 128 + 255) / 256, 256, 0, stream>>>(Wm1, BTws);

  // ---- conv1 ----
  k_lin_dual128<<<512, 256, 0, stream>>>(x, W1l, W1r, b1l, R0, R1, N);  // q1,p1
  k_agg<<<512, 256, 0, stream>>>(R0, R1, rowptr, csrsrc, R2, stats1, N); // hpre1
  k_finalize<<<1, 64, 0, stream>>>(stats1, g1, be1, N);

  // ---- conv2 (BN1+relu fused into the consumer) ----
  k_lin_dual64<<<512, 256, 0, stream>>>(R2, stats1, W2l, W2r, b2l, R0, R1, N); // q2,p2
  k_agg<<<512, 256, 0, stream>>>(R0, R1, rowptr, csrsrc, R2, stats2, N); // hpre2
  k_finalize<<<1, 64, 0, stream>>>(stats2, g2, be2, N);

  // ---- per-node u/v (BN2+relu fused) ----
  k_lin2_dual<<<512, 256, 0, stream>>>(R2, stats2, Wm1, bm1, U, V, N);

  // ---- fused edge MLP over dst-ordered edges ----
  k_edge<<<512, 256, 0, stream>>>(U, V, attr, csrsrc, csrdst, csreid,
                                  W2Tws, BTws, bm2, Wm3, bm3, out, E);
}

// Round 6
// 973.838 us; speedup vs baseline: 1.4558x; 1.4558x over previous
//
#include <hip/hip_runtime.h>
#include <hip/hip_fp16.h>

// ---------------------------------------------------------------------------
// EdgeClassifierGNN: 2x SAGEConv(mean)+BN+ReLU, then 3-layer edge MLP.
// Trick 1: lin_l before mean-aggregation (64-wide gather).
// Trick 2: edge-MLP layer 1 split: z1 = relu(u[src] + v[dst] + B1*attr).
// Trick 3: CSR by dst -> atomic-free aggregation.
// Trick 4: all node linears via one register-blocked GEMM (BN fused on input,
//          weights pre-concatenated k-major).
// Trick 5: k_edge LDS in fp16 (Z1, W2T) -> ~39 KB -> 4 blocks/CU for latency
//          hiding (round-4 evidence: k_edge is gather-latency-bound).
// Round-6 fix: W2h is 4096 half2 = 4096 FLOATS of ws (16 KB), not 2048 —
//          rowptr was being overwritten by k_prep -> GPU fault.
// ---------------------------------------------------------------------------

#define EPS 1e-5f

// ---------------- CSR build ----------------
__global__ __launch_bounds__(256) void k_hist(
    const int* __restrict__ dst, int* __restrict__ deg, int E) {
  int e = blockIdx.x * 256 + threadIdx.x;
  if (e < E) atomicAdd(&deg[dst[e]], 1);
}

__global__ __launch_bounds__(1024) void k_scan(
    const int* __restrict__ deg, int* __restrict__ rowptr,
    int* __restrict__ cursor, int N) {
  __shared__ int wsum[16];
  __shared__ int carry;
  const int lane = threadIdx.x & 63;
  const int w    = threadIdx.x >> 6;
  if (threadIdx.x == 0) carry = 0;
  __syncthreads();
  for (int base = 0; base < N; base += 1024) {
    int i = base + threadIdx.x;
    int v = (i < N) ? deg[i] : 0;
    int incl = v;
#pragma unroll
    for (int off = 1; off < 64; off <<= 1) {
      int t = __shfl_up(incl, off);
      if (lane >= off) incl += t;
    }
    if (lane == 63) wsum[w] = incl;
    __syncthreads();
    if (w == 0) {
      int ws_ = (lane < 16) ? wsum[lane] : 0;
      int wincl = ws_;
#pragma unroll
      for (int off = 1; off < 16; off <<= 1) {
        int t = __shfl_up(wincl, off);
        if (lane >= off) wincl += t;
      }
      if (lane < 16) wsum[lane] = wincl;
    }
    __syncthreads();
    int woff = carry + (w > 0 ? wsum[w - 1] : 0);
    int excl = woff + incl - v;
    if (i < N) { rowptr[i] = excl; cursor[i] = excl; }
    int tot = wsum[15];
    __syncthreads();
    if (threadIdx.x == 0) carry += tot;
    __syncthreads();
  }
  if (threadIdx.x == 0) rowptr[N] = carry;
}

__global__ __launch_bounds__(256) void k_fill(
    const int* __restrict__ src, const int* __restrict__ dst,
    int* __restrict__ cursor, int* __restrict__ csr_src, int E) {
  int e = blockIdx.x * 256 + threadIdx.x;
  if (e < E) {
    int pos = atomicAdd(&cursor[dst[e]], 1);
    csr_src[pos] = src[e];
  }
}

// ---------------- weight prep (k-major concatenated layouts) ----------------
__global__ __launch_bounds__(256) void k_prep(
    const float* __restrict__ W1l, const float* __restrict__ W1r,
    const float* __restrict__ b1l,
    const float* __restrict__ W2l, const float* __restrict__ W2r,
    const float* __restrict__ b2l,
    const float* __restrict__ Wm1, const float* __restrict__ bm1,
    const float* __restrict__ Wm2,
    float* __restrict__ Wt1, float* __restrict__ Wt2, float* __restrict__ Wt3,
    float* __restrict__ bias1, float* __restrict__ bias2,
    float* __restrict__ bias3, float* __restrict__ BT,
    __half2* __restrict__ W2h) {
  int idx = blockIdx.x * 256 + threadIdx.x;
  if (idx < 16384) {  // Wt1 [128k x 128f] = [W1l | W1r]^T
    int k = idx >> 7, f = idx & 127;
    Wt1[idx] = (f < 64) ? W1l[f * 128 + k] : W1r[(f - 64) * 128 + k];
    return;
  }
  idx -= 16384;
  if (idx < 8192) {   // Wt2 [64k x 128f] = [W2l | W2r]^T
    int k = idx >> 7, f = idx & 127;
    Wt2[idx] = (f < 64) ? W2l[f * 64 + k] : W2r[(f - 64) * 64 + k];
    return;
  }
  idx -= 8192;
  if (idx < 16384) {  // Wt3 [64k x 256f] = [A1 | C1]^T  (col slices of Wm1)
    int k = idx >> 8, f = idx & 255;
    Wt3[idx] = (f < 128) ? Wm1[f * 144 + k] : Wm1[(f - 128) * 144 + 80 + k];
    return;
  }
  idx -= 16384;
  if (idx < 128) { bias1[idx] = (idx < 64) ? 0.f : b1l[idx - 64]; return; }
  idx -= 128;
  if (idx < 128) { bias2[idx] = (idx < 64) ? 0.f : b2l[idx - 64]; return; }
  idx -= 128;
  if (idx < 256) { bias3[idx] = (idx < 128) ? bm1[idx] : 0.f; return; }
  idx -= 256;
  if (idx < 2048) {   // BT [16k x 128c] = attr-slice of Wm1, fp32
    int k = idx >> 7, c = idx & 127;
    BT[idx] = Wm1[c * 144 + 64 + k];
    return;
  }
  idx -= 2048;
  if (idx < 4096) {   // W2h [128k x 32 half2] = Wm2^T in fp16
    int k = idx >> 5, fp = idx & 31;
    W2h[idx] = __floats2half2_rn(Wm2[(2 * fp) * 128 + k],
                                 Wm2[(2 * fp + 1) * 128 + k]);
    return;
  }
}

// ---------------- register-blocked node GEMM ----------------
// C[n][f0+f] = bias[f0+f] + sum_k Xeff[n][k] * Wt[k][f0+f]
// Xeff = stats ? relu(X*sc+sh) : X. Tile 64n x 128f, BK=32, 4x8 acc/thread.
template<int K>
__global__ __launch_bounds__(256) void k_gemm(
    const float* __restrict__ X, const float* __restrict__ stats,
    const float* __restrict__ Wt, const float* __restrict__ bias,
    float* __restrict__ C, int N, int Ftot) {
  __shared__ __align__(16) float Xs[32][68];
  __shared__ __align__(16) float Ws_[32][128];
  const int tid = threadIdx.x;
  const int tx  = tid & 15;   // 8 feats [8tx..)
  const int ty  = tid >> 4;   // 4 nodes [4ty..)
  const int f0  = blockIdx.y * 128;
  const int n0  = blockIdx.x * 64;
  float acc[4][8];
#pragma unroll
  for (int j = 0; j < 8; ++j) {
    float bv = bias[f0 + 8 * tx + j];
#pragma unroll
    for (int i = 0; i < 4; ++i) acc[i][j] = bv;
  }
  for (int k0 = 0; k0 < K; k0 += 32) {
    __syncthreads();
    // stage X-tile (transposed to k-major), BN+relu fused
#pragma unroll
    for (int l = 0; l < 2; ++l) {
      int idx = tid * 2 + l;
      int kq = idx & 7, n = idx >> 3;
      float4 xv = make_float4(0.f, 0.f, 0.f, 0.f);
      if (n0 + n < N) xv = *(const float4*)&X[(size_t)(n0 + n) * K + k0 + kq * 4];
      if (stats) {
        int kb = k0 + kq * 4;
        xv.x = fmaxf(xv.x * stats[128 + kb + 0] + stats[192 + kb + 0], 0.f);
        xv.y = fmaxf(xv.y * stats[128 + kb + 1] + stats[192 + kb + 1], 0.f);
        xv.z = fmaxf(xv.z * stats[128 + kb + 2] + stats[192 + kb + 2], 0.f);
        xv.w = fmaxf(xv.w * stats[128 + kb + 3] + stats[192 + kb + 3], 0.f);
      }
      Xs[kq * 4 + 0][n] = xv.x;
      Xs[kq * 4 + 1][n] = xv.y;
      Xs[kq * 4 + 2][n] = xv.z;
      Xs[kq * 4 + 3][n] = xv.w;
    }
    // stage W-tile (already k-major)
#pragma unroll
    for (int l = 0; l < 4; ++l) {
      int idx = tid + l * 256;
      int kr = idx >> 5, fc = idx & 31;
      *(float4*)&Ws_[kr][fc * 4] =
          *(const float4*)&Wt[(size_t)(k0 + kr) * Ftot + f0 + fc * 4];
    }
    __syncthreads();
#pragma unroll
    for (int kk = 0; kk < 32; ++kk) {
      float4 a  = *(const float4*)&Xs[kk][4 * ty];
      float4 b0 = *(const float4*)&Ws_[kk][8 * tx];
      float4 b1 = *(const float4*)&Ws_[kk][8 * tx + 4];
      float aa[4] = {a.x, a.y, a.z, a.w};
      float bb[8] = {b0.x, b0.y, b0.z, b0.w, b1.x, b1.y, b1.z, b1.w};
#pragma unroll
      for (int i = 0; i < 4; ++i)
#pragma unroll
        for (int j = 0; j < 8; ++j) acc[i][j] += aa[i] * bb[j];
    }
  }
#pragma unroll
  for (int i = 0; i < 4; ++i) {
    int n = n0 + 4 * ty + i;
    if (n < N) {
      float* cp = C + (size_t)n * Ftot + f0 + 8 * tx;
      *(float4*)cp = make_float4(acc[i][0], acc[i][1], acc[i][2], acc[i][3]);
      *(float4*)(cp + 4) = make_float4(acc[i][4], acc[i][5], acc[i][6], acc[i][7]);
    }
  }
}

// ---------------- fused aggregate + mean + residual + BN stats ----------------
// hpre[n][f] = (sum_{j in row n} qb[csr[j]*qs+f]) / max(deg,1) + pb[n*qs+f]
__global__ __launch_bounds__(256) void k_agg(
    const float* __restrict__ qb, const float* __restrict__ pb, int qs,
    const int* __restrict__ rowptr, const int* __restrict__ csr_src,
    float* __restrict__ hpre, float* __restrict__ stats, int N) {
  __shared__ float red[512];
  const int f  = threadIdx.x & 63;
  const int ns = threadIdx.x >> 6;
  float lsum = 0.f, lsq = 0.f;
  for (int n = blockIdx.x * 4 + ns; n < N; n += gridDim.x * 4) {
    const int r0 = rowptr[n], r1 = rowptr[n + 1];
    float s0 = 0.f, s1 = 0.f, s2 = 0.f, s3 = 0.f;
    int j = r0;
    for (; j + 3 < r1; j += 4) {
      int a0 = csr_src[j], a1 = csr_src[j + 1];
      int a2 = csr_src[j + 2], a3 = csr_src[j + 3];
      s0 += qb[(size_t)a0 * qs + f];
      s1 += qb[(size_t)a1 * qs + f];
      s2 += qb[(size_t)a2 * qs + f];
      s3 += qb[(size_t)a3 * qs + f];
    }
    for (; j < r1; ++j) s0 += qb[(size_t)csr_src[j] * qs + f];
    float c = (float)(r1 - r0);
    c = c > 1.f ? c : 1.f;
    float v = ((s0 + s1) + (s2 + s3)) / c + pb[(size_t)n * qs + f];
    hpre[(size_t)n * 64 + f] = v;
    lsum += v;
    lsq  += v * v;
  }
  red[threadIdx.x]       = lsum;
  red[256 + threadIdx.x] = lsq;
  __syncthreads();
  if (threadIdx.x < 64) {
    float ts = red[f] + red[f + 64] + red[f + 128] + red[f + 192];
    float tq = red[256 + f] + red[256 + f + 64] + red[256 + f + 128] + red[256 + f + 192];
    atomicAdd(&stats[f], ts);
    atomicAdd(&stats[64 + f], tq);
  }
}

// stats -> BN scale/shift: sc=g*invstd, sh=be-mean*sc
__global__ void k_finalize(float* stats, const float* __restrict__ g,
                           const float* __restrict__ be, int N) {
  int f = threadIdx.x;  // 64 threads
  float inv_n = 1.0f / (float)N;
  float mean = stats[f] * inv_n;
  float var  = stats[64 + f] * inv_n - mean * mean;
  float s = g[f] * rsqrtf(var + EPS);
  stats[128 + f] = s;
  stats[192 + f] = be[f] - mean * s;
}

// ---------------------------------------------------------------------------
// Fused edge MLP. UV[n][256] = [u|v]. Per 64-edge tile (original edge order):
//   z1[e][c] = relu(u[src[e]][c] + v[dst[e]][c] + attr[e]·BT[:,c])  (fp16 LDS)
//   z2 = relu(z1 @ W2T + bm2) (fp16 weights in LDS, fp32 accum)
//   out = z2 @ Wm3.T + bm3 (fused via LDS atomics)
// LDS = 16K(W2h) + 16.5K(Z1h) + 4K(attr) + 1K misc ~= 38.8 KB -> 4 blocks/CU.
// ---------------------------------------------------------------------------
__global__ __launch_bounds__(256, 4) void k_edge(
    const float* __restrict__ UV, const float* __restrict__ attr,
    const int* __restrict__ src, const int* __restrict__ dst,
    const __half2* __restrict__ W2hws, const float* __restrict__ BTws,
    const float* __restrict__ bm2, const float* __restrict__ Wm3,
    const float* __restrict__ bm3, float* __restrict__ out, int E) {
  __shared__ __align__(16) __half2 W2h[128 * 32];  // [k][half2-col] 16 KB
  __shared__ __align__(16) __half2 Z1h[64 * 66];   // [e][half2-col] 16.5 KB
  __shared__ __align__(16) float attrL[64 * 16];   // 4 KB
  __shared__ int   idxL[128];
  __shared__ float outT[128];

  const int tid = threadIdx.x;
  const int c4  = tid & 31;
  const int tx  = tid & 15;
  const int ty  = tid >> 4;

  for (int i = tid; i < 1024; i += 256)
    ((uint4*)W2h)[i] = ((const uint4*)W2hws)[i];

  const float4* uv4 = (const float4*)UV;   // 64 float4 per node row
  const float4* at4 = (const float4*)attr;
  const float4* bt4 = (const float4*)BTws;

  const int nt = (E + 63) >> 6;
  for (int t = blockIdx.x; t < nt; t += gridDim.x) {
    const int e0 = t << 6;
    __syncthreads();   // protect LDS vs previous iteration (incl. W2h staging)

    if (tid < 64)       idxL[tid] = (e0 + tid < E) ? src[e0 + tid] : 0;
    else if (tid < 128) idxL[tid] = (e0 + tid - 64 < E) ? dst[e0 + tid - 64] : 0;
    if (tid < 128) outT[tid] = bm3[tid & 1];
    {
      int a0 = e0 * 4 + tid;
      float4 av = make_float4(0.f, 0.f, 0.f, 0.f);
      if (a0 < E * 4) av = at4[a0];
      ((float4*)attrL)[tid] = av;
    }
    float4 breg[16];
#pragma unroll
    for (int k = 0; k < 16; ++k) breg[k] = bt4[k * 32 + c4];
    __syncthreads();

    // ---- layer 1: 64 edges x 32 float4-chunks, write fp16 Z1 ----
#pragma unroll
    for (int it = 0; it < 8; ++it) {
      const int e = it * 8 + (tid >> 5);
      float4 a = uv4[(size_t)idxL[e] * 64 + c4];             // u chunk
      float4 b = uv4[(size_t)idxL[64 + e] * 64 + 32 + c4];   // v chunk
      float sx = a.x + b.x, sy = a.y + b.y, sz = a.z + b.z, sw = a.w + b.w;
#pragma unroll
      for (int k = 0; k < 16; ++k) {
        float av = attrL[e * 16 + k];
        sx += av * breg[k].x; sy += av * breg[k].y;
        sz += av * breg[k].z; sw += av * breg[k].w;
      }
      Z1h[e * 66 + 2 * c4]     = __floats2half2_rn(fmaxf(sx, 0.f), fmaxf(sy, 0.f));
      Z1h[e * 66 + 2 * c4 + 1] = __floats2half2_rn(fmaxf(sz, 0.f), fmaxf(sw, 0.f));
    }
    __syncthreads();

    // ---- layer 2: [64e x 64c], K=128, 4x4/thread, fp16 loads fp32 math ----
    float acc[4][4];
#pragma unroll
    for (int c = 0; c < 4; ++c) {
      float bv = bm2[4 * tx + c];
#pragma unroll
      for (int i = 0; i < 4; ++i) acc[i][c] = bv;
    }
    for (int kk = 0; kk < 128; kk += 4) {
      float aa[4][4], bb[4][4];
#pragma unroll
      for (int i = 0; i < 4; ++i) {
        uint2 ra = *reinterpret_cast<const uint2*>(&Z1h[(4 * ty + i) * 66 + (kk >> 1)]);
        float2 lo = __half22float2(*reinterpret_cast<__half2*>(&ra.x));
        float2 hi = __half22float2(*reinterpret_cast<__half2*>(&ra.y));
        aa[i][0] = lo.x; aa[i][1] = lo.y; aa[i][2] = hi.x; aa[i][3] = hi.y;
      }
#pragma unroll
      for (int q = 0; q < 4; ++q) {
        uint2 rb = *reinterpret_cast<const uint2*>(&W2h[(kk + q) * 32 + 2 * tx]);
        float2 lo = __half22float2(*reinterpret_cast<__half2*>(&rb.x));
        float2 hi = __half22float2(*reinterpret_cast<__half2*>(&rb.y));
        bb[q][0] = lo.x; bb[q][1] = lo.y; bb[q][2] = hi.x; bb[q][3] = hi.y;
      }
#pragma unroll
      for (int i = 0; i < 4; ++i)
#pragma unroll
        for (int q = 0; q < 4; ++q)
#pragma unroll
          for (int c = 0; c < 4; ++c) acc[i][c] += aa[i][q] * bb[q][c];
    }

    // ---- fused layer 3 ----
    float w30[4], w31[4];
#pragma unroll
    for (int c = 0; c < 4; ++c) {
      w30[c] = Wm3[4 * tx + c];
      w31[c] = Wm3[64 + 4 * tx + c];
    }
#pragma unroll
    for (int i = 0; i < 4; ++i) {
      float p0 = 0.f, p1 = 0.f;
#pragma unroll
      for (int c = 0; c < 4; ++c) {
        float z = fmaxf(acc[i][c], 0.f);
        p0 += z * w30[c];
        p1 += z * w31[c];
      }
      atomicAdd(&outT[(4 * ty + i) * 2 + 0], p0);
      atomicAdd(&outT[(4 * ty + i) * 2 + 1], p1);
    }
    __syncthreads();

    if (tid < 128) {
      int e = tid >> 1;
      if (e0 + e < E) out[(size_t)(e0 + e) * 2 + (tid & 1)] = outT[tid];
    }
  }
}

extern "C" void kernel_launch(void* const* d_in, const int* in_sizes, int n_in,
                              void* d_out, int out_size, void* d_ws, size_t ws_size,
                              hipStream_t stream) {
  const float* x    = (const float*)d_in[0];
  const int*   ei   = (const int*)d_in[1];
  const float* attr = (const float*)d_in[2];
  const float* W1l  = (const float*)d_in[3];
  const float* b1l  = (const float*)d_in[4];
  const float* W1r  = (const float*)d_in[5];
  const float* g1   = (const float*)d_in[6];
  const float* be1  = (const float*)d_in[7];
  const float* W2l  = (const float*)d_in[8];
  const float* b2l  = (const float*)d_in[9];
  const float* W2r  = (const float*)d_in[10];
  const float* g2   = (const float*)d_in[11];
  const float* be2  = (const float*)d_in[12];
  const float* Wm1  = (const float*)d_in[13];
  const float* bm1  = (const float*)d_in[14];
  const float* Wm2  = (const float*)d_in[15];
  const float* bm2  = (const float*)d_in[16];
  const float* Wm3  = (const float*)d_in[17];
  const float* bm3  = (const float*)d_in[18];
  float* out = (float*)d_out;

  const int N = in_sizes[0] / 128;
  const int E = in_sizes[1] / 2;
  const int* srcI = ei;
  const int* dstI = ei + E;

  float* ws = (float*)d_ws;
  const size_t NF = (size_t)N * 64;
  // overlaid float regions:
  float* H2 = ws;                 // [N][64]
  float* C1 = ws + NF;            // [N][128]  (q|p) — also reused as C2
  float* H1 = ws + 3 * NF;        // [N][64]
  float* UV = ws + NF;            // [N][256]  (u|v) — overlays C1+H1 (dead)
  float* small  = ws + 5 * NF;
  float* stats1 = small;          // 256
  float* stats2 = stats1 + 256;   // 256
  float* Wt1    = stats2 + 256;   // 128*128
  float* Wt2    = Wt1 + 16384;    // 64*128
  float* Wt3    = Wt2 + 8192;     // 64*256
  float* bias1  = Wt3 + 16384;    // 128
  float* bias2  = bias1 + 128;    // 128
  float* bias3  = bias2 + 128;    // 256
  float* BTws   = bias3 + 256;    // 16*128
  __half2* W2h  = (__half2*)(BTws + 2048);  // 4096 half2 = 16 KB = 4096 floats
  int* rowptr = (int*)(BTws + 2048 + 4096); // N+1   (FIX: was +2048 — overlap!)
  int* cursor = rowptr + (N + 1);           // N
  int* deg    = cursor + N;                 // N
  int* csrsrc = deg + N;                    // E

  hipMemsetAsync(deg, 0, (size_t)N * sizeof(int), stream);
  hipMemsetAsync(stats1, 0, 512 * sizeof(float), stream);

  // ---- CSR build + weight prep ----
  const int eBlocks = (E + 255) / 256;
  k_hist<<<eBlocks, 256, 0, stream>>>(dstI, deg, E);
  k_scan<<<1, 1024, 0, stream>>>(deg, rowptr, cursor, N);
  k_fill<<<eBlocks, 256, 0, stream>>>(srcI, dstI, cursor, csrsrc, E);
  k_prep<<<(47616 + 255) / 256, 256, 0, stream>>>(
      W1l, W1r, b1l, W2l, W2r, b2l, Wm1, bm1, Wm2,
      Wt1, Wt2, Wt3, bias1, bias2, bias3, BTws, W2h);

  const int mTiles = (N + 63) / 64;

  // ---- conv1: C1 = [x@W1l^T | x@W1r^T + b1l] ----
  k_gemm<128><<<dim3(mTiles, 1), 256, 0, stream>>>(x, nullptr, Wt1, bias1, C1, N, 128);
  k_agg<<<1024, 256, 0, stream>>>(C1, C1 + 64, 128, rowptr, csrsrc, H1, stats1, N);
  k_finalize<<<1, 64, 0, stream>>>(stats1, g1, be1, N);

  // ---- conv2 (BN1+relu fused into GEMM input) ----
  k_gemm<64><<<dim3(mTiles, 1), 256, 0, stream>>>(H1, stats1, Wt2, bias2, C1, N, 128);
  k_agg<<<1024, 256, 0, stream>>>(C1, C1 + 64, 128, rowptr, csrsrc, H2, stats2, N);
  k_finalize<<<1, 64, 0, stream>>>(stats2, g2, be2, N);

  // ---- UV = [h2@A1^T + bm1 | h2@C1^T] (BN2+relu fused) ----
  k_gemm<64><<<dim3(mTiles, 2), 256, 0, stream>>>(H2, stats2, Wt3, bias3, UV, N, 256);

  // ---- fused edge MLP ----
  k_edge<<<1024, 256, 0, stream>>>(UV, attr, srcI, dstI, W2h, BTws,
                                   bm2, Wm3, bm3, out, E);
}